// Round 6
// baseline (345.886 us; speedup 1.0000x reference)
//
#include <hip/hip_runtime.h>

#define BATCH 16384
#define NUM   512
#define CONS  512
#define RPW   32                    // rows per wave/block
#define ASTR  64                    // LDS bytes per atom (32 rows * 2B)
#define ZOFF  (NUM*ASTR)            // 128 B zeros scratch (neg dummies, 2 parities)
#define OOFF  (NUM*ASTR + 128)      // 128 B ones scratch (pos dummies)
#define LDSB  (NUM*ASTR + 256)      // 33024
#define NPAD  (CONS + 4)
#define EPC   24                    // words per (c,g): 10 neg, 10 pos, ho, fl, 2 pad

typedef _Float16 h4 __attribute__((ext_vector_type(4)));   // 4 rows, 8 B
static __device__ __forceinline__ h4 hmax4(h4 a, h4 b){ return __builtin_elementwise_max(a,b); }
static __device__ __forceinline__ h4 hmin4(h4 a, h4 b){ return __builtin_elementwise_min(a,b); }
static __device__ __forceinline__ uint2 h2u2(h4 h){ return __builtin_bit_cast(uint2,h); }
static __device__ __forceinline__ h4 u22h(uint2 u){ return __builtin_bit_cast(h4,u); }

// flags: 0 sign | 1 N1 | 2 P1 | 3 N2 | 4 P2 | 5 PR1 | 6 PR2
__global__ __launch_bounds__(64) void prep_kernel(
    const float* __restrict__ pos, const float* __restrict__ neg,
    const int* __restrict__ head_atom, const int* __restrict__ head_sign,
    unsigned* __restrict__ ents) {
  int c = blockIdx.x, lane = threadIdx.x;
  unsigned* E = ents + (size_t)c * (8 * EPC);
  for (int t = lane; t < 8 * EPC; t += 64) {         // dummy prefill (also pads c>=CONS)
    int g = t / EPC, k = t % EPC;
    unsigned v = 0;
    if (k < 10) v = ZOFF + (unsigned)(g & 1) * 64u;
    else if (k < 20) v = OOFF + (unsigned)(g & 1) * 64u;
    else if (k == 20) v = ZOFF;
    E[t] = v;
  }
  if (c >= CONS) return;
  __shared__ int cN[2], cP[2], sN, sP, flg;
  __shared__ unsigned short spN[16], spP[16];
  if (lane < 2) { cN[lane] = 0; cP[lane] = 0; }
  if (lane == 2) sN = 0;
  if (lane == 3) sP = 0;
  if (lane == 4) flg = 0;
  __syncthreads();                                    // also orders prefill stores
  int hp1 = (c >= 1) ? head_atom[c-1] : -1;
  int hp2 = (c >= 2) ? head_atom[c-2] : -1;
  for (int k = 0; k < NUM/64; ++k) {
    int a = k * 64 + lane;
    if (neg[(size_t)c*NUM + a] != 0.f) {
      if (a == hp1) atomicOr(&flg, 2);
      else if (a == hp2) atomicOr(&flg, 8);
      else {
        int par = a & 1;
        int r = atomicAdd(&cN[par], 1);
        if (r < 40) E[(par + 2*(r&3))*EPC + (r>>2)] = (unsigned)a * 64u;
        else { int j = atomicAdd(&sN, 1); if (j < 16) spN[j] = (unsigned short)a; }
      }
    }
    if (pos[(size_t)c*NUM + a] != 0.f) {
      if (a == hp1) atomicOr(&flg, 4);
      else if (a == hp2) atomicOr(&flg, 16);
      else {
        int par = a & 1;
        int r = atomicAdd(&cP[par], 1);
        if (r < 40) E[(par + 2*(r&3))*EPC + 10 + (r>>2)] = (unsigned)a * 64u;
        else { int j = atomicAdd(&sP, 1); if (j < 16) spP[j] = (unsigned short)a; }
      }
    }
  }
  __syncthreads();
  if (lane == 0) {
    int n = sN > 16 ? 16 : sN;                        // rare: parity overflow spill
    for (int j = 0; j < n; ++j) {
      int a = spN[j], q = (a & 1) ^ 1;
      if (cN[q] < 40) { int r = cN[q]++; E[(q + 2*(r&3))*EPC + (r>>2)] = (unsigned)a * 64u; }
    }
    n = sP > 16 ? 16 : sP;
    for (int j = 0; j < n; ++j) {
      int a = spP[j], q = (a & 1) ^ 1;
      if (cP[q] < 40) { int r = cP[q]++; E[(q + 2*(r&3))*EPC + 10 + (r>>2)] = (unsigned)a * 64u; }
    }
    int hc = head_atom[c];
    unsigned f = (unsigned)flg | (head_sign[c] ? 1u : 0u);
    if (hc == hp1) f |= 32u; else if (hc == hp2) f |= 64u;
    unsigned ho = (unsigned)hc * 64u;
    for (int g = 0; g < 8; ++g) { E[g*EPC + 20] = ho; E[g*EPC + 21] = f; }
  }
}

struct ENT { uint4 e0, e1, e2, e3, e4, e5; };
struct RD  { h4 r[21]; unsigned ho, fl; };
struct ST  { h4 braw, prevraw; unsigned ho, fl; };

static __device__ __forceinline__ ENT ldent(const uint4* T, unsigned c, unsigned g) {
  unsigned b = (c * 8u + g) * 6u;
  ENT e; e.e0=T[b]; e.e1=T[b+1]; e.e2=T[b+2]; e.e3=T[b+3]; e.e4=T[b+4]; e.e5=T[b+5];
  return e;
}
static __device__ __forceinline__ void issue_reads(const ENT& E, const char* Pb,
                                                   unsigned pr8, RD& R) {
  R.r[0]  = *(const h4*)(Pb + (E.e0.x + pr8));
  R.r[1]  = *(const h4*)(Pb + (E.e0.y + pr8));
  R.r[2]  = *(const h4*)(Pb + (E.e0.z + pr8));
  R.r[3]  = *(const h4*)(Pb + (E.e0.w + pr8));
  R.r[4]  = *(const h4*)(Pb + (E.e1.x + pr8));
  R.r[5]  = *(const h4*)(Pb + (E.e1.y + pr8));
  R.r[6]  = *(const h4*)(Pb + (E.e1.z + pr8));
  R.r[7]  = *(const h4*)(Pb + (E.e1.w + pr8));
  R.r[8]  = *(const h4*)(Pb + (E.e2.x + pr8));
  R.r[9]  = *(const h4*)(Pb + (E.e2.y + pr8));
  R.r[10] = *(const h4*)(Pb + (E.e2.z + pr8));
  R.r[11] = *(const h4*)(Pb + (E.e2.w + pr8));
  R.r[12] = *(const h4*)(Pb + (E.e3.x + pr8));
  R.r[13] = *(const h4*)(Pb + (E.e3.y + pr8));
  R.r[14] = *(const h4*)(Pb + (E.e3.z + pr8));
  R.r[15] = *(const h4*)(Pb + (E.e3.w + pr8));
  R.r[16] = *(const h4*)(Pb + (E.e4.x + pr8));
  R.r[17] = *(const h4*)(Pb + (E.e4.y + pr8));
  R.r[18] = *(const h4*)(Pb + (E.e4.z + pr8));
  R.r[19] = *(const h4*)(Pb + (E.e4.w + pr8));
  R.r[20] = *(const h4*)(Pb + (E.e5.x + pr8));       // prev of head atom
  R.ho = E.e5.x; R.fl = E.e5.y;
}
template<int CTRL>
static __device__ __forceinline__ h4 dppmax(h4 x) {
  uint2 u = h2u2(x), v;
  v.x = (unsigned)__builtin_amdgcn_mov_dpp((int)u.x, CTRL, 0xF, 0xF, true);
  v.y = (unsigned)__builtin_amdgcn_mov_dpp((int)u.y, CTRL, 0xF, 0xF, true);
  return hmax4(x, u22h(v));
}
static __device__ __forceinline__ void combine(const RD& R, ST& S) {
  h4 aN = hmax4(hmax4(hmax4(R.r[0],R.r[1]), hmax4(R.r[2],R.r[3])),
                hmax4(hmax4(R.r[4],R.r[5]), hmax4(R.r[6],R.r[7])));
  aN = hmax4(aN, hmax4(R.r[8], R.r[9]));
  h4 aP = hmin4(hmin4(hmin4(R.r[10],R.r[11]), hmin4(R.r[12],R.r[13])),
                hmin4(hmin4(R.r[14],R.r[15]), hmin4(R.r[16],R.r[17])));
  aP = hmin4(aP, hmin4(R.r[18], R.r[19]));
  const h4 one4 = {(_Float16)1.f,(_Float16)1.f,(_Float16)1.f,(_Float16)1.f};
  h4 bp = hmax4(aN, one4 - aP);
  bp = dppmax<0xB1>(bp);    // quad_perm xor1
  bp = dppmax<0x4E>(bp);    // quad_perm xor2
  bp = dppmax<0x141>(bp);   // row_half_mirror = xor7 within 8
  S.braw = bp; S.prevraw = R.r[20]; S.ho = R.ho; S.fl = R.fl;
}
static __device__ __forceinline__ h4 finalize(const ST& S, h4 up1, h4 up2,
                                              char* Pb, unsigned pr8, int lane) {
  const h4 one4 = {(_Float16)1.f,(_Float16)1.f,(_Float16)1.f,(_Float16)1.f};
  unsigned fl = S.fl;
  uint2 body = h2u2(S.braw);
  uint2 u1 = h2u2(up1), u2v = h2u2(up2);
  uint2 i1 = h2u2(one4 - up1), i2 = h2u2(one4 - up2);
  unsigned mN1 = 0u-((fl>>1)&1u), mP1 = 0u-((fl>>2)&1u);
  unsigned mN2 = 0u-((fl>>3)&1u), mP2 = 0u-((fl>>4)&1u);
  h4 b = u22h(body);
  b = hmax4(b, u22h(uint2{u1.x & mN1, u1.y & mN1}));
  b = hmax4(b, u22h(uint2{i1.x & mP1, i1.y & mP1}));
  b = hmax4(b, u22h(uint2{u2v.x & mN2, u2v.y & mN2}));
  b = hmax4(b, u22h(uint2{i2.x & mP2, i2.y & mP2}));
  unsigned mR1 = 0u-((fl>>5)&1u), mR2 = 0u-((fl>>6)&1u), mRn = ~(mR1|mR2);
  uint2 pv = h2u2(S.prevraw);
  h4 prev = u22h(uint2{(u1.x&mR1)|(u2v.x&mR2)|(pv.x&mRn),
                       (u1.y&mR1)|(u2v.y&mR2)|(pv.y&mRn)});
  unsigned ms = 0u-(fl&1u);
  uint2 hi = h2u2(hmax4(prev, one4 - b));
  uint2 lo = h2u2(hmin4(prev, b));
  h4 upd = u22h(uint2{(hi.x&ms)|(lo.x&~ms), (hi.y&ms)|(lo.y&~ms)});
  if ((lane & 7) == 0) *(h4*)(Pb + S.ho + pr8) = upd;
  return upd;
}

__global__ __launch_bounds__(64) void solve_kernel(
    const float* __restrict__ preds,
    const unsigned* __restrict__ ents,
    float* __restrict__ out) {
  __shared__ char Pb[LDSB];
  const int lane = threadIdx.x;
  const int g = lane & 7;                 // literal group
  const unsigned pr8 = (unsigned)(lane >> 3) * 8u;   // row-quad byte offset
  const size_t row0 = (size_t)blockIdx.x * RPW;

  if (lane < 32) *(unsigned*)(Pb + ZOFF + lane*4) = 0u;
  else           *(unsigned*)(Pb + OOFF + (lane-32)*4) = 0x3C003C00u;

  // stage: lane -> (rq = lane&7, atom a = it*8 + lane>>3); banks spread, b64 writes
  {
    const int rq = lane & 7, ab = lane >> 3;
    for (int it = 0; it < 64; ++it) {
      int a = it * 8 + ab;
      const float* s0 = preds + (row0 + rq*4) * NUM + a;
      h4 h;
      h.x = (_Float16)s0[0];
      h.y = (_Float16)s0[NUM];
      h.z = (_Float16)s0[2*NUM];
      h.w = (_Float16)s0[3*NUM];
      *(h4*)(Pb + a*ASTR + rq*8) = h;
    }
  }
  __syncthreads();

  const uint4* T = (const uint4*)ents;
  ENT E0 = ldent(T, 0u, (unsigned)g);
  ENT E1 = ldent(T, 1u, (unsigned)g);
  ENT Ea = ldent(T, 2u, (unsigned)g);
  ENT Eb = ldent(T, 3u, (unsigned)g);
  RD R0, RA, RB; ST S0, S1;
  issue_reads(E0, Pb, pr8, R0);
  issue_reads(E1, Pb, pr8, RB);
  combine(R0, S0);
  h4 up1 = (h4)0.0f, up2 = (h4)0.0f;

  #pragma unroll 1
  for (int i = 0; i < CONS; i += 2) {
    issue_reads(Ea, Pb, pr8, RA);                                  // reads(i+2)
    { h4 u = finalize(S0, up1, up2, Pb, pr8, lane); up2 = up1; up1 = u; }  // A(i)
    combine(RB, S1);                                               // stage(i+1)
    Ea = ldent(T, (unsigned)(i + 4), (unsigned)g);
    issue_reads(Eb, Pb, pr8, RB);                                  // reads(i+3)
    { h4 u = finalize(S1, up1, up2, Pb, pr8, lane); up2 = up1; up1 = u; }  // A(i+1)
    combine(RA, S0);                                               // stage(i+2)
    Eb = ldent(T, (unsigned)(i + 5), (unsigned)g);
  }

  __syncthreads();
  {
    const int rq = lane & 7, ab = lane >> 3;
    for (int it = 0; it < 64; ++it) {
      int a = it * 8 + ab;
      h4 h = *(const h4*)(Pb + a*ASTR + rq*8);
      float* d0 = out + (row0 + rq*4) * NUM + a;
      d0[0]     = (float)h.x;
      d0[NUM]   = (float)h.y;
      d0[2*NUM] = (float)h.z;
      d0[3*NUM] = (float)h.w;
    }
  }
}

extern "C" void kernel_launch(void* const* d_in, const int* in_sizes, int n_in,
                              void* d_out, int out_size, void* d_ws, size_t ws_size,
                              hipStream_t stream) {
  (void)in_sizes; (void)n_in; (void)out_size; (void)ws_size;
  const float* preds     = (const float*)d_in[0];
  const float* pos       = (const float*)d_in[1];
  const float* neg       = (const float*)d_in[2];
  const int*   head_atom = (const int*)d_in[3];
  const int*   head_sign = (const int*)d_in[4];

  unsigned* ents = (unsigned*)d_ws;    // NPAD * 8 * EPC * 4 = 396 KB

  prep_kernel<<<NPAD, 64, 0, stream>>>(pos, neg, head_atom, head_sign, ents);
  solve_kernel<<<BATCH / RPW, 64, 0, stream>>>(preds, ents, (float*)d_out);
}